// Round 4
// baseline (1702.548 us; speedup 1.0000x reference)
//
#include <hip/hip_runtime.h>
#include <stdint.h>
#include <type_traits>

#define NE 8
#define NH 128
#define ND 8
#define NCONT 168
#define NHOR 24
#define NB 4096
#define NG 512   // 4*NH
#define BT 64    // batch rows per block

typedef float f32x4 __attribute__((ext_vector_type(4)));
typedef float f32x2 __attribute__((ext_vector_type(2)));
typedef short bf16x8 __attribute__((ext_vector_type(8)));
typedef unsigned int u32x2 __attribute__((ext_vector_type(2)));

__device__ __forceinline__ unsigned short f2bf(float f){
  union { float f; unsigned u; } v; v.f = f;
  unsigned r = (v.u + 0x7FFFu + ((v.u >> 16) & 1u)) >> 16;
  return (unsigned short)r;
}
__device__ __forceinline__ unsigned cvt_pk_bf16(float lo, float hi){
  unsigned r;
  asm("v_cvt_pk_bf16_f32 %0, %1, %2" : "=v"(r) : "v"(lo), "v"(hi));
  return r;
}

__device__ __forceinline__ f32x2 splat2(float v){ f32x2 r; r.x = v; r.y = v; return r; }
__device__ __forceinline__ f32x2 lo2(f32x4 v){ return __builtin_shufflevector(v, v, 0, 1); }
__device__ __forceinline__ f32x2 hi2(f32x4 v){ return __builtin_shufflevector(v, v, 2, 3); }
__device__ __forceinline__ f32x2 fma2(f32x2 a, f32x2 b, f32x2 c){
  return __builtin_elementwise_fma(a, b, c);
}
__device__ __forceinline__ f32x2 med2(f32x2 x, float lo, float hi){
  f32x2 o;
  o.x = __builtin_amdgcn_fmed3f(x.x, lo, hi);
  o.y = __builtin_amdgcn_fmed3f(x.y, lo, hi);
  return o;
}
// 2 reciprocals for the price of 1 trans op: r = rcp(q0*q1); 1/q0 = r*q1, 1/q1 = r*q0
__device__ __forceinline__ f32x2 inv2(f32x2 q){
  float pr = q.x * q.y;
  float r  = __builtin_amdgcn_rcpf(pr);
  f32x2 o; o.x = r * q.y; o.y = r * q.x; return o;
}

// Eigen-style rational tanh: x clamped to +-7.9053111, err ~1e-7.
__device__ __forceinline__ f32x2 tanh2(f32x2 x){
  x = med2(x, -7.90531110763549805f, 7.90531110763549805f);
  f32x2 t = x * x;
  f32x2 p = fma2(t, splat2(-2.76076847742355e-16f), splat2(2.00018790482477e-13f));
  p = fma2(p, t, splat2(-8.60467152213735e-11f));
  p = fma2(p, t, splat2(5.12229709037114e-08f));
  p = fma2(p, t, splat2(1.48572235717979e-05f));
  p = fma2(p, t, splat2(6.37261928875436e-04f));
  p = fma2(p, t, splat2(4.89352455891786e-03f));
  f32x2 q = fma2(t, splat2(1.19825839466702e-06f), splat2(1.18534705686654e-04f));
  q = fma2(q, t, splat2(2.26843463243900e-03f));
  q = fma2(q, t, splat2(4.89352518554385e-03f));
  return (x * p) * inv2(q);
}

// sigmoid(x) = 0.5 + 0.5*tanh(x/2), scale folded into coefficients; clamp +-15.81.
__device__ __forceinline__ f32x2 sigm2(f32x2 x){
  x = med2(x, -15.8106222152709961f, 15.8106222152709961f);
  f32x2 t = x * x;
  f32x2 p = fma2(t, splat2(-1.68503935489719e-20f), splat2(4.88327125201360e-17f));
  p = fma2(p, t, splat2(-8.40299953333725e-14f));
  p = fma2(p, t, splat2(2.00089730170748e-10f));
  p = fma2(p, t, splat2(2.32144118309342e-07f));
  p = fma2(p, t, splat2(3.98288705547148e-05f));
  p = fma2(p, t, splat2(1.22338113972947e-03f));
  f32x2 q = fma2(t, splat2(1.87227874166722e-08f), splat2(7.40841910541588e-06f));
  q = fma2(q, t, splat2(5.67108658109750e-04f));
  q = fma2(q, t, splat2(4.89352518554385e-03f));
  return fma2(x * p, inv2(q), splat2(0.5f));
}

__global__ void prep_fxw_enc(const float* __restrict__ feats, const float* __restrict__ W,
                             const float* __restrict__ bias, float* __restrict__ out){
  int idx = blockIdx.x * blockDim.x + threadIdx.x;
  if (idx >= NE * NCONT * NG) return;
  int j = idx & (NG - 1);
  int t = (idx >> 9) % NCONT;
  int e = idx / (NCONT * NG);
  float s = bias[e * NG + j];
  #pragma unroll
  for (int i = 0; i < ND; ++i)
    s += feats[t * ND + i] * W[(e * 9 + 1 + i) * NG + j];
  out[idx] = s;
}

__global__ void prep_fxw_dec(const float* __restrict__ feats, const float* __restrict__ W,
                             const float* __restrict__ bias, float* __restrict__ out){
  int idx = blockIdx.x * blockDim.x + threadIdx.x;
  if (idx >= NE * NHOR * NG) return;
  int j = idx & (NG - 1);
  int t = (idx >> 9) % NHOR;
  int e = idx / (NHOR * NG);
  float s = bias[e * NG + j];
  #pragma unroll
  for (int i = 0; i < ND; ++i)
    s += feats[(NCONT + t) * ND + i] * W[(e * ND + i) * NG + j];
  out[idx] = s;
}

__global__ void prep_node(const int* __restrict__ nid, const float* __restrict__ emb,
                          float* __restrict__ node_w){
  int b = blockIdx.x * blockDim.x + threadIdx.x;
  if (b >= NB) return;
  int n = nid[b];
  float a[NE]; float s = 0.f;
  #pragma unroll
  for (int e = 0; e < NE; ++e){ a[e] = fabsf(emb[n * NE + e]); s += a[e]; }
  float inv = 1.0f / s;
  #pragma unroll
  for (int e = 0; e < NE; ++e) node_w[b * NE + e] = a[e] * inv;
}

// One block = (expert e, 64 batch rows). 512 threads = 8 waves.
// MFMA roles: A = U^T frags (regs), B = h frags (LDS), C = z^T (fx as C-in).
// Cell math: packed f32x2 rational sigmoid/tanh (v_pk_fma_f32), ~no trans ops.
__global__ __launch_bounds__(512, 2) void lstm_main(
    const float* __restrict__ y_prev,
    const float* __restrict__ enc_W,
    const float* __restrict__ enc_U,
    const float* __restrict__ dec_U,
    const float* __restrict__ out_w,
    const float* __restrict__ fxw_enc,
    const float* __restrict__ fxw_dec,
    float* __restrict__ ws_out)
{
  __shared__ unsigned short hl[2][BT * NH];  // 2 x 16 KB, XOR-swizzled rows
  __shared__ float part[2][BT][9];           // decoder partials (+1 pad col)

  const int tid  = threadIdx.x;
  const int lane = tid & 63;
  const int w    = tid >> 6;
  const int e    = blockIdx.x & 7;
  const int b0   = (blockIdx.x >> 3) * BT;
  const int l15  = lane & 15;
  const int l4   = lane >> 4;              // 0..3
  const int hc0  = w * 16 + l4 * 4;        // thread's hidden-col base (rg adds 0..3)

  // precomputed swizzled LDS byte addresses (step-invariant)
  const int q   = (l15 >> 2) & 1;
  const int Ae  = l15 * 128 + ((l4 ^ (l15 & 3)) << 3);
  const int rb0 = 2 * (Ae + q * 32);
  const int rb1 = 2 * (Ae + (1 - q) * 32);
  const int wb  = 2 * ((l15 * 128 + hc0) ^ ((l15 & 7) << 3));

  { // init h buffer 0 = 0
    f32x4 z4 = {0.f, 0.f, 0.f, 0.f};
    ((f32x4*)&hl[0][0])[tid]       = z4;
    ((f32x4*)&hl[0][0])[tid + 512] = z4;
  }

  // A-frags: ut[g][kc], lane holds U[k = 32kc+8*l4+j][128g + w*16 + l15]
  bf16x8 ut[4][4];
  {
    const float* Ub = enc_U + e * NH * NG + w * 16 + l15;
    #pragma unroll
    for (int g = 0; g < 4; ++g)
      #pragma unroll
      for (int kc = 0; kc < 4; ++kc){
        const float* p = Ub + (kc * 32 + l4 * 8) * NG + g * NH;
        bf16x8 v;
        #pragma unroll
        for (int j = 0; j < 8; ++j) v[j] = (short)f2bf(p[j * NG]);
        ut[g][kc] = v;
      }
  }

  // encoder y-weight row, packed halves
  f32x2 w042[4][2];
  #pragma unroll
  for (int g = 0; g < 4; ++g){
    f32x4 t4 = *(const f32x4*)&enc_W[(e * 9) * NG + g * NH + hc0];
    w042[g][0] = lo2(t4); w042[g][1] = hi2(t4);
  }

  f32x2 cs2[4][2];   // cell state, packed
  #pragma unroll
  for (int nf = 0; nf < 4; ++nf){ cs2[nf][0] = splat2(0.f); cs2[nf][1] = splat2(0.f); }

  f32x2 ow2[2];      // decoder out weights (set later)
  f32x4 fxv[4];      // prefetched fx for current step
  float yv[4];       // prefetched y for current step

  const float* fxe = fxw_enc + e * NCONT * NG;
  const float* yp  = y_prev + b0;

  // prologue prefetch t=0
  #pragma unroll
  for (int g = 0; g < 4; ++g) fxv[g] = *(const f32x4*)&fxe[g * NH + hc0];
  #pragma unroll
  for (int nf = 0; nf < 4; ++nf) yv[nf] = yp[nf * 16 + l15];

  __syncthreads();

  // ---- one LSTM step; B = source buffer parity; prefetches next step's fx/y ----
  auto step = [&](auto Bc, auto ENCc, const float* fxn, const float* ypn, float* pout){
    constexpr int  B   = decltype(Bc)::value;
    constexpr bool ENC = decltype(ENCc)::value;

    float ycur[4];
    if constexpr (ENC){
      #pragma unroll
      for (int nf = 0; nf < 4; ++nf) ycur[nf] = yv[nf];
    }

    f32x4 acc[4][4];  // [nf][gate]
    #pragma unroll
    for (int kc = 0; kc < 4; ++kc){
      bf16x8 hb[4];
      #pragma unroll
      for (int nf = 0; nf < 4; ++nf)
        hb[nf] = *(const bf16x8*)((const char*)hl +
                   (B * 16384 + nf * 4096 + (kc >> 1) * 128) + ((kc & 1) ? rb1 : rb0));
      #pragma unroll
      for (int nf = 0; nf < 4; ++nf)
        #pragma unroll
        for (int g = 0; g < 4; ++g){
          if (kc == 0)
            acc[nf][g] = __builtin_amdgcn_mfma_f32_16x16x32_bf16(ut[g][0], hb[nf], fxv[g], 0, 0, 0);
          else
            acc[nf][g] = __builtin_amdgcn_mfma_f32_16x16x32_bf16(ut[g][kc], hb[nf], acc[nf][g], 0, 0, 0);
        }
    }

    // prefetch next step's fx (and y) -- latency hidden under cell math
    #pragma unroll
    for (int g = 0; g < 4; ++g) fxv[g] = *(const f32x4*)&fxn[g * NH + hc0];
    if constexpr (ENC){
      #pragma unroll
      for (int nf = 0; nf < 4; ++nf) yv[nf] = ypn[nf * 16 + l15];
    }

    #pragma unroll
    for (int nf = 0; nf < 4; ++nf){
      f32x2 h2[2];
      #pragma unroll
      for (int hf = 0; hf < 2; ++hf){
        f32x2 zi = hf ? hi2(acc[nf][0]) : lo2(acc[nf][0]);
        f32x2 zf = hf ? hi2(acc[nf][1]) : lo2(acc[nf][1]);
        f32x2 zg = hf ? hi2(acc[nf][2]) : lo2(acc[nf][2]);
        f32x2 zo = hf ? hi2(acc[nf][3]) : lo2(acc[nf][3]);
        if constexpr (ENC){
          f32x2 y2 = splat2(ycur[nf]);
          zi = fma2(y2, w042[0][hf], zi);
          zf = fma2(y2, w042[1][hf], zf);
          zg = fma2(y2, w042[2][hf], zg);
          zo = fma2(y2, w042[3][hf], zo);
        }
        f32x2 gi = sigm2(zi), gf = sigm2(zf);
        f32x2 gg = tanh2(zg), go = sigm2(zo);
        f32x2 c  = fma2(gf, cs2[nf][hf], gi * gg);
        cs2[nf][hf] = c;
        h2[hf] = go * tanh2(c);
      }
      u32x2 pk;
      pk.x = cvt_pk_bf16(h2[0].x, h2[0].y);
      pk.y = cvt_pk_bf16(h2[1].x, h2[1].y);
      *(u32x2*)((char*)hl + ((B ^ 1) * 16384 + nf * 4096) + wb) = pk;
      if constexpr (!ENC){
        f32x2 pp = fma2(h2[0], ow2[0], h2[1] * ow2[1]);
        pout[nf] = pp.x + pp.y;
      }
    }
    __syncthreads();
  };

  // ---------------- encoder: 168 steps ----------------
  for (int t = 0; t < NCONT; t += 2){
    step(std::integral_constant<int,0>{}, std::true_type{}, fxe + NG, yp + NB, nullptr);
    const float* fx2 = (t + 2 < NCONT) ? fxe + 2 * NG : fxe;
    const float* yp2 = (t + 2 < NCONT) ? yp + 2 * NB  : yp;
    step(std::integral_constant<int,1>{}, std::true_type{}, fx2, yp2, nullptr);
    fxe += 2 * NG; yp += 2 * NB;
  }

  // decoder A-frags
  {
    const float* Ub = dec_U + e * NH * NG + w * 16 + l15;
    #pragma unroll
    for (int g = 0; g < 4; ++g)
      #pragma unroll
      for (int kc = 0; kc < 4; ++kc){
        const float* p = Ub + (kc * 32 + l4 * 8) * NG + g * NH;
        bf16x8 v;
        #pragma unroll
        for (int j = 0; j < 8; ++j) v[j] = (short)f2bf(p[j * NG]);
        ut[g][kc] = v;
      }
  }
  {
    f32x4 ow4 = *(const f32x4*)&out_w[e * NH + hc0];
    ow2[0] = lo2(ow4); ow2[1] = hi2(ow4);
  }

  const float* fxd = fxw_dec + e * NHOR * NG;
  #pragma unroll
  for (int g = 0; g < 4; ++g) fxv[g] = *(const f32x4*)&fxd[g * NH + hc0];

  auto emit = [&](int t, float* pbuf){
    #pragma unroll
    for (int nf = 0; nf < 4; ++nf){
      pbuf[nf] += __shfl_xor(pbuf[nf], 16);
      pbuf[nf] += __shfl_xor(pbuf[nf], 32);
    }
    int pb = t & 1;
    if (lane < 16){
      #pragma unroll
      for (int nf = 0; nf < 4; ++nf) part[pb][nf * 16 + l15][w] = pbuf[nf];
    }
    __syncthreads();
    if (w == 0){
      float s = 0.f;
      #pragma unroll
      for (int ww = 0; ww < 8; ++ww) s += part[pb][lane][ww];
      ws_out[(e * NHOR + t) * NB + b0 + lane] = s;
    }
  };

  // ---------------- decoder: 24 steps ----------------
  #pragma unroll 1
  for (int td = 0; td < NHOR; td += 2){
    float pbuf[4];
    step(std::integral_constant<int,0>{}, std::false_type{}, fxd + NG, nullptr, pbuf);
    emit(td, pbuf);
    const float* fx2 = (td + 2 < NHOR) ? fxd + 2 * NG : fxd;
    step(std::integral_constant<int,1>{}, std::false_type{}, fx2, nullptr, pbuf);
    emit(td + 1, pbuf);
    fxd += 2 * NG;
  }
}

__global__ void finalize(const float* __restrict__ ws_out, const float* __restrict__ node_w,
                         float* __restrict__ out){
  int idx = blockIdx.x * blockDim.x + threadIdx.x;
  if (idx >= NHOR * NB) return;
  int b = idx & (NB - 1);
  float s = 0.f;
  #pragma unroll
  for (int e = 0; e < NE; ++e)
    s += ws_out[e * NHOR * NB + idx] * node_w[b * NE + e];
  out[idx] = s;
}

extern "C" void kernel_launch(void* const* d_in, const int* in_sizes, int n_in,
                              void* d_out, int out_size, void* d_ws, size_t ws_size,
                              hipStream_t stream) {
  const float* feats  = (const float*)d_in[0];
  const float* y_prev = (const float*)d_in[1];
  const int*   nid    = (const int*)  d_in[2];
  const float* emb    = (const float*)d_in[3];
  const float* enc_W  = (const float*)d_in[4];
  const float* enc_U  = (const float*)d_in[5];
  const float* enc_b  = (const float*)d_in[6];
  const float* dec_W  = (const float*)d_in[7];
  const float* dec_U  = (const float*)d_in[8];
  const float* dec_b  = (const float*)d_in[9];
  const float* out_w  = (const float*)d_in[10];
  float* out = (float*)d_out;

  float* ws      = (float*)d_ws;
  float* fxw_enc = ws;
  float* fxw_dec = fxw_enc + NE * NCONT * NG;
  float* node_w  = fxw_dec + NE * NHOR * NG;
  float* ws_out  = node_w + NB * NE;

  prep_fxw_enc<<<(NE * NCONT * NG + 255) / 256, 256, 0, stream>>>(feats, enc_W, enc_b, fxw_enc);
  prep_fxw_dec<<<(NE * NHOR * NG + 255) / 256, 256, 0, stream>>>(feats, dec_W, dec_b, fxw_dec);
  prep_node<<<(NB + 255) / 256, 256, 0, stream>>>(nid, emb, node_w);
  lstm_main<<<NE * (NB / BT), 512, 0, stream>>>(y_prev, enc_W, enc_U, dec_U, out_w,
                                                fxw_enc, fxw_dec, ws_out);
  finalize<<<(NHOR * NB + 255) / 256, 256, 0, stream>>>(ws_out, node_w, out);
}

// Round 5
// 1119.918 us; speedup vs baseline: 1.5202x; 1.5202x over previous
//
#include <hip/hip_runtime.h>
#include <stdint.h>
#include <type_traits>

#define NE 8
#define NH 128
#define ND 8
#define NCONT 168
#define NHOR 24
#define NB 4096
#define NG 512   // 4*NH
#define BT 64    // batch rows per block

// gate input scales folded into weights: i,f,o -> -log2(e); g -> +2*log2(e)
#define S_SIG (-1.44269504088896f)
#define S_TANH (2.88539008177793f)

typedef float f32x4 __attribute__((ext_vector_type(4)));
typedef float f32x2 __attribute__((ext_vector_type(2)));
typedef short bf16x8 __attribute__((ext_vector_type(8)));
typedef unsigned int u32x2 __attribute__((ext_vector_type(2)));

__device__ __forceinline__ unsigned short f2bf(float f){
  union { float f; unsigned u; } v; v.f = f;
  unsigned r = (v.u + 0x7FFFu + ((v.u >> 16) & 1u)) >> 16;
  return (unsigned short)r;
}
__device__ __forceinline__ unsigned cvt_pk_bf16(float lo, float hi){
  unsigned r;
  asm("v_cvt_pk_bf16_f32 %0, %1, %2" : "=v"(r) : "v"(lo), "v"(hi));
  return r;
}

__device__ __forceinline__ f32x2 splat2(float v){ f32x2 r; r.x = v; r.y = v; return r; }
__device__ __forceinline__ f32x2 lo2(f32x4 v){ return __builtin_shufflevector(v, v, 0, 1); }
__device__ __forceinline__ f32x2 hi2(f32x4 v){ return __builtin_shufflevector(v, v, 2, 3); }
__device__ __forceinline__ f32x2 fma2(f32x2 a, f32x2 b, f32x2 c){
  return __builtin_elementwise_fma(a, b, c);
}
__device__ __forceinline__ f32x2 exp2_2(f32x2 x){
  f32x2 o; o.x = __builtin_amdgcn_exp2f(x.x); o.y = __builtin_amdgcn_exp2f(x.y); return o;
}
__device__ __forceinline__ f32x2 rcp2(f32x2 x){
  f32x2 o; o.x = __builtin_amdgcn_rcpf(x.x); o.y = __builtin_amdgcn_rcpf(x.y); return o;
}
// with z pre-scaled by -log2e: sigmoid = rcp(1 + exp2(z_s))
// with z pre-scaled by +2log2e: r = rcp(1+exp2(z_s)); tanh = 1 - 2r
__device__ __forceinline__ f32x2 gate2(f32x2 zs){
  return rcp2(exp2_2(zs) + splat2(1.0f));
}

__global__ void prep_fxw_enc(const float* __restrict__ feats, const float* __restrict__ W,
                             const float* __restrict__ bias, float* __restrict__ out){
  int idx = blockIdx.x * blockDim.x + threadIdx.x;
  if (idx >= NE * NCONT * NG) return;
  int j = idx & (NG - 1);
  int t = (idx >> 9) % NCONT;
  int e = idx / (NCONT * NG);
  float s = bias[e * NG + j];
  #pragma unroll
  for (int i = 0; i < ND; ++i)
    s += feats[t * ND + i] * W[(e * 9 + 1 + i) * NG + j];
  float sc = ((j >> 7) == 2) ? S_TANH : S_SIG;
  out[idx] = s * sc;
}

__global__ void prep_fxw_dec(const float* __restrict__ feats, const float* __restrict__ W,
                             const float* __restrict__ bias, float* __restrict__ out){
  int idx = blockIdx.x * blockDim.x + threadIdx.x;
  if (idx >= NE * NHOR * NG) return;
  int j = idx & (NG - 1);
  int t = (idx >> 9) % NHOR;
  int e = idx / (NHOR * NG);
  float s = bias[e * NG + j];
  #pragma unroll
  for (int i = 0; i < ND; ++i)
    s += feats[(NCONT + t) * ND + i] * W[(e * ND + i) * NG + j];
  float sc = ((j >> 7) == 2) ? S_TANH : S_SIG;
  out[idx] = s * sc;
}

__global__ void prep_node(const int* __restrict__ nid, const float* __restrict__ emb,
                          float* __restrict__ node_w){
  int b = blockIdx.x * blockDim.x + threadIdx.x;
  if (b >= NB) return;
  int n = nid[b];
  float a[NE]; float s = 0.f;
  #pragma unroll
  for (int e = 0; e < NE; ++e){ a[e] = fabsf(emb[n * NE + e]); s += a[e]; }
  float inv = 1.0f / s;
  #pragma unroll
  for (int e = 0; e < NE; ++e) node_w[b * NE + e] = a[e] * inv;
}

// One block = (expert e, 64 batch rows). 512 threads = 8 waves.
// MFMA roles: A = U^T frags (regs, pre-scaled per gate), B = h frags (LDS),
// C-in = pre-scaled fx. Gates: rcp(1+exp2(z_s)) only — scales folded into
// weights; cell state kept as c_s = 2log2e * c so tanh(c) needs no mul.
__global__ __launch_bounds__(512, 2) void lstm_main(
    const float* __restrict__ y_prev,
    const float* __restrict__ enc_W,
    const float* __restrict__ enc_U,
    const float* __restrict__ dec_U,
    const float* __restrict__ out_w,
    const float* __restrict__ fxw_enc,
    const float* __restrict__ fxw_dec,
    float* __restrict__ ws_out)
{
  __shared__ unsigned short hl[2][BT * NH];  // 2 x 16 KB, XOR-swizzled rows
  __shared__ float part[2][BT][9];           // decoder partials (+1 pad col)

  const int tid  = threadIdx.x;
  const int lane = tid & 63;
  const int w    = tid >> 6;
  const int e    = blockIdx.x & 7;
  const int b0   = (blockIdx.x >> 3) * BT;
  const int l15  = lane & 15;
  const int l4   = lane >> 4;              // 0..3
  const int hc0  = w * 16 + l4 * 4;        // thread's hidden-col base (rg adds 0..3)

  // precomputed swizzled LDS byte addresses (step-invariant)
  const int q   = (l15 >> 2) & 1;
  const int Ae  = l15 * 128 + ((l4 ^ (l15 & 3)) << 3);
  const int rb0 = 2 * (Ae + q * 32);
  const int rb1 = 2 * (Ae + (1 - q) * 32);
  const int wb  = 2 * ((l15 * 128 + hc0) ^ ((l15 & 7) << 3));

  { // init h buffer 0 = 0
    f32x4 z4 = {0.f, 0.f, 0.f, 0.f};
    ((f32x4*)&hl[0][0])[tid]       = z4;
    ((f32x4*)&hl[0][0])[tid + 512] = z4;
  }

  // A-frags: ut[g][kc], lane holds sc[g]*U[k = 32kc+8*l4+j][128g + w*16 + l15]
  bf16x8 ut[4][4];
  {
    const float* Ub = enc_U + e * NH * NG + w * 16 + l15;
    #pragma unroll
    for (int g = 0; g < 4; ++g){
      float scg = (g == 2) ? S_TANH : S_SIG;
      #pragma unroll
      for (int kc = 0; kc < 4; ++kc){
        const float* p = Ub + (kc * 32 + l4 * 8) * NG + g * NH;
        bf16x8 v;
        #pragma unroll
        for (int j = 0; j < 8; ++j) v[j] = (short)f2bf(p[j * NG] * scg);
        ut[g][kc] = v;
      }
    }
  }

  // encoder y-weight row, packed halves, pre-scaled
  f32x2 w042[4][2];
  #pragma unroll
  for (int g = 0; g < 4; ++g){
    float scg = (g == 2) ? S_TANH : S_SIG;
    f32x4 t4 = *(const f32x4*)&enc_W[(e * 9) * NG + g * NH + hc0];
    t4 *= scg;
    w042[g][0] = lo2(t4); w042[g][1] = hi2(t4);
  }

  f32x2 cs2[4][2];   // scaled cell state c_s = 2log2e * c
  #pragma unroll
  for (int nf = 0; nf < 4; ++nf){ cs2[nf][0] = splat2(0.f); cs2[nf][1] = splat2(0.f); }

  f32x2 ow2[2];      // decoder out weights (set later)
  f32x4 fxv[4];      // prefetched fx for current step
  float yv[4];       // prefetched y for current step

  const float* fxe = fxw_enc + e * NCONT * NG;
  const float* yp  = y_prev + b0;

  // prologue prefetch t=0
  #pragma unroll
  for (int g = 0; g < 4; ++g) fxv[g] = *(const f32x4*)&fxe[g * NH + hc0];
  #pragma unroll
  for (int nf = 0; nf < 4; ++nf) yv[nf] = yp[nf * 16 + l15];

  __syncthreads();

  // ---- one LSTM step; B = source buffer parity; prefetches next step's fx/y ----
  auto step = [&](auto Bc, auto ENCc, const float* fxn, const float* ypn, float* pout){
    constexpr int  B   = decltype(Bc)::value;
    constexpr bool ENC = decltype(ENCc)::value;

    float ycur[4];
    if constexpr (ENC){
      #pragma unroll
      for (int nf = 0; nf < 4; ++nf) ycur[nf] = yv[nf];
    }

    f32x4 acc[4][4];  // [nf][gate]
    #pragma unroll
    for (int kc = 0; kc < 4; ++kc){
      bf16x8 hb[4];
      #pragma unroll
      for (int nf = 0; nf < 4; ++nf)
        hb[nf] = *(const bf16x8*)((const char*)hl +
                   (B * 16384 + nf * 4096 + (kc >> 1) * 128) + ((kc & 1) ? rb1 : rb0));
      #pragma unroll
      for (int nf = 0; nf < 4; ++nf)
        #pragma unroll
        for (int g = 0; g < 4; ++g){
          if (kc == 0)
            acc[nf][g] = __builtin_amdgcn_mfma_f32_16x16x32_bf16(ut[g][0], hb[nf], fxv[g], 0, 0, 0);
          else
            acc[nf][g] = __builtin_amdgcn_mfma_f32_16x16x32_bf16(ut[g][kc], hb[nf], acc[nf][g], 0, 0, 0);
        }
    }

    // prefetch next step's fx (and y) -- latency hidden under cell math
    #pragma unroll
    for (int g = 0; g < 4; ++g) fxv[g] = *(const f32x4*)&fxn[g * NH + hc0];
    if constexpr (ENC){
      #pragma unroll
      for (int nf = 0; nf < 4; ++nf) yv[nf] = ypn[nf * 16 + l15];
    }

    #pragma unroll
    for (int nf = 0; nf < 4; ++nf){
      f32x2 h2[2];
      #pragma unroll
      for (int hf = 0; hf < 2; ++hf){
        f32x2 zi = hf ? hi2(acc[nf][0]) : lo2(acc[nf][0]);
        f32x2 zf = hf ? hi2(acc[nf][1]) : lo2(acc[nf][1]);
        f32x2 zg = hf ? hi2(acc[nf][2]) : lo2(acc[nf][2]);
        f32x2 zo = hf ? hi2(acc[nf][3]) : lo2(acc[nf][3]);
        if constexpr (ENC){
          f32x2 y2 = splat2(ycur[nf]);
          zi = fma2(y2, w042[0][hf], zi);
          zf = fma2(y2, w042[1][hf], zf);
          zg = fma2(y2, w042[2][hf], zg);
          zo = fma2(y2, w042[3][hf], zo);
        }
        f32x2 gi = gate2(zi);                 // sigmoid(i)
        f32x2 gf = gate2(zf);                 // sigmoid(f)
        f32x2 go = gate2(zo);                 // sigmoid(o)
        f32x2 rg_ = gate2(zg);                // rcp(1+exp2(zg_s))
        // gg2 = 2log2e * tanh(g) = fma(rg, -4log2e, 2log2e)
        f32x2 gg2 = fma2(rg_, splat2(-2.0f * S_TANH), splat2(S_TANH));
        f32x2 c  = fma2(gf, cs2[nf][hf], gi * gg2);   // scaled cell state
        cs2[nf][hf] = c;
        f32x2 rc = gate2(c);                  // rcp(1+exp2(c_s))
        f32x2 th = fma2(rc, splat2(-2.0f), splat2(1.0f));  // tanh(c)
        h2[hf] = go * th;
      }
      u32x2 pk;
      pk.x = cvt_pk_bf16(h2[0].x, h2[0].y);
      pk.y = cvt_pk_bf16(h2[1].x, h2[1].y);
      *(u32x2*)((char*)hl + ((B ^ 1) * 16384 + nf * 4096) + wb) = pk;
      if constexpr (!ENC){
        f32x2 pp = fma2(h2[0], ow2[0], h2[1] * ow2[1]);
        pout[nf] = pp.x + pp.y;
      }
    }
    __syncthreads();
  };

  // ---------------- encoder: 168 steps ----------------
  for (int t = 0; t < NCONT; t += 2){
    step(std::integral_constant<int,0>{}, std::true_type{}, fxe + NG, yp + NB, nullptr);
    const float* fx2 = (t + 2 < NCONT) ? fxe + 2 * NG : fxe;
    const float* yp2 = (t + 2 < NCONT) ? yp + 2 * NB  : yp;
    step(std::integral_constant<int,1>{}, std::true_type{}, fx2, yp2, nullptr);
    fxe += 2 * NG; yp += 2 * NB;
  }

  // decoder A-frags (pre-scaled)
  {
    const float* Ub = dec_U + e * NH * NG + w * 16 + l15;
    #pragma unroll
    for (int g = 0; g < 4; ++g){
      float scg = (g == 2) ? S_TANH : S_SIG;
      #pragma unroll
      for (int kc = 0; kc < 4; ++kc){
        const float* p = Ub + (kc * 32 + l4 * 8) * NG + g * NH;
        bf16x8 v;
        #pragma unroll
        for (int j = 0; j < 8; ++j) v[j] = (short)f2bf(p[j * NG] * scg);
        ut[g][kc] = v;
      }
    }
  }
  {
    f32x4 ow4 = *(const f32x4*)&out_w[e * NH + hc0];
    ow2[0] = lo2(ow4); ow2[1] = hi2(ow4);
  }

  const float* fxd = fxw_dec + e * NHOR * NG;
  #pragma unroll
  for (int g = 0; g < 4; ++g) fxv[g] = *(const f32x4*)&fxd[g * NH + hc0];

  auto emit = [&](int t, float* pbuf){
    #pragma unroll
    for (int nf = 0; nf < 4; ++nf){
      pbuf[nf] += __shfl_xor(pbuf[nf], 16);
      pbuf[nf] += __shfl_xor(pbuf[nf], 32);
    }
    int pb = t & 1;
    if (lane < 16){
      #pragma unroll
      for (int nf = 0; nf < 4; ++nf) part[pb][nf * 16 + l15][w] = pbuf[nf];
    }
    __syncthreads();
    if (w == 0){
      float s = 0.f;
      #pragma unroll
      for (int ww = 0; ww < 8; ++ww) s += part[pb][lane][ww];
      ws_out[(e * NHOR + t) * NB + b0 + lane] = s;
    }
  };

  // ---------------- decoder: 24 steps ----------------
  #pragma unroll 1
  for (int td = 0; td < NHOR; td += 2){
    float pbuf[4];
    step(std::integral_constant<int,0>{}, std::false_type{}, fxd + NG, nullptr, pbuf);
    emit(td, pbuf);
    const float* fx2 = (td + 2 < NHOR) ? fxd + 2 * NG : fxd;
    step(std::integral_constant<int,1>{}, std::false_type{}, fx2, nullptr, pbuf);
    emit(td + 1, pbuf);
    fxd += 2 * NG;
  }
}

__global__ void finalize(const float* __restrict__ ws_out, const float* __restrict__ node_w,
                         float* __restrict__ out){
  int idx = blockIdx.x * blockDim.x + threadIdx.x;
  if (idx >= NHOR * NB) return;
  int b = idx & (NB - 1);
  float s = 0.f;
  #pragma unroll
  for (int e = 0; e < NE; ++e)
    s += ws_out[e * NHOR * NB + idx] * node_w[b * NE + e];
  out[idx] = s;
}

extern "C" void kernel_launch(void* const* d_in, const int* in_sizes, int n_in,
                              void* d_out, int out_size, void* d_ws, size_t ws_size,
                              hipStream_t stream) {
  const float* feats  = (const float*)d_in[0];
  const float* y_prev = (const float*)d_in[1];
  const int*   nid    = (const int*)  d_in[2];
  const float* emb    = (const float*)d_in[3];
  const float* enc_W  = (const float*)d_in[4];
  const float* enc_U  = (const float*)d_in[5];
  const float* enc_b  = (const float*)d_in[6];
  const float* dec_W  = (const float*)d_in[7];
  const float* dec_U  = (const float*)d_in[8];
  const float* dec_b  = (const float*)d_in[9];
  const float* out_w  = (const float*)d_in[10];
  float* out = (float*)d_out;

  float* ws      = (float*)d_ws;
  float* fxw_enc = ws;
  float* fxw_dec = fxw_enc + NE * NCONT * NG;
  float* node_w  = fxw_dec + NE * NHOR * NG;
  float* ws_out  = node_w + NB * NE;

  prep_fxw_enc<<<(NE * NCONT * NG + 255) / 256, 256, 0, stream>>>(feats, enc_W, enc_b, fxw_enc);
  prep_fxw_dec<<<(NE * NHOR * NG + 255) / 256, 256, 0, stream>>>(feats, dec_W, dec_b, fxw_dec);
  prep_node<<<(NB + 255) / 256, 256, 0, stream>>>(nid, emb, node_w);
  lstm_main<<<NE * (NB / BT), 512, 0, stream>>>(y_prev, enc_W, enc_U, dec_U, out_w,
                                                fxw_enc, fxw_dec, ws_out);
  finalize<<<(NHOR * NB + 255) / 256, 256, 0, stream>>>(ws_out, node_w, out);
}

// Round 9
// 1100.122 us; speedup vs baseline: 1.5476x; 1.0180x over previous
//
#include <hip/hip_runtime.h>
#include <stdint.h>
#include <type_traits>

#define NE 8
#define NH 128
#define ND 8
#define NCONT 168
#define NHOR 24
#define NB 4096
#define NG 512   // 4*NH
#define BT 64    // batch rows per block

// gate input scales folded into weights: i,f,o -> -log2(e); g -> +2*log2(e)
#define S_SIG (-1.44269504088896f)
#define S_TANH (2.88539008177793f)

typedef float f32x4 __attribute__((ext_vector_type(4)));
typedef float f32x2 __attribute__((ext_vector_type(2)));
typedef short bf16x8 __attribute__((ext_vector_type(8)));
typedef unsigned int u32x2 __attribute__((ext_vector_type(2)));

template <int N> using ic = std::integral_constant<int, N>;

__device__ __forceinline__ unsigned short f2bf(float f){
  union { float f; unsigned u; } v; v.f = f;
  unsigned r = (v.u + 0x7FFFu + ((v.u >> 16) & 1u)) >> 16;
  return (unsigned short)r;
}
__device__ __forceinline__ unsigned cvt_pk_bf16(float lo, float hi){
  unsigned r;
  asm("v_cvt_pk_bf16_f32 %0, %1, %2" : "=v"(r) : "v"(lo), "v"(hi));
  return r;
}

__device__ __forceinline__ f32x2 splat2(float v){ f32x2 r; r.x = v; r.y = v; return r; }
__device__ __forceinline__ f32x2 lo2(f32x4 v){ return __builtin_shufflevector(v, v, 0, 1); }
__device__ __forceinline__ f32x2 hi2(f32x4 v){ return __builtin_shufflevector(v, v, 2, 3); }
__device__ __forceinline__ f32x2 fma2(f32x2 a, f32x2 b, f32x2 c){
  return __builtin_elementwise_fma(a, b, c);
}
__device__ __forceinline__ f32x2 exp2_2(f32x2 x){
  f32x2 o; o.x = __builtin_amdgcn_exp2f(x.x); o.y = __builtin_amdgcn_exp2f(x.y); return o;
}
__device__ __forceinline__ f32x2 rcp2(f32x2 x){
  f32x2 o; o.x = __builtin_amdgcn_rcpf(x.x); o.y = __builtin_amdgcn_rcpf(x.y); return o;
}
// with z pre-scaled by -log2e: sigmoid = rcp(1 + exp2(z_s))
// with z pre-scaled by +2log2e: r = rcp(1+exp2(z_s)); tanh = 1 - 2r
__device__ __forceinline__ f32x2 gate2(f32x2 zs){
  return rcp2(exp2_2(zs) + splat2(1.0f));
}

__global__ void prep_fxw_enc(const float* __restrict__ feats, const float* __restrict__ W,
                             const float* __restrict__ bias, float* __restrict__ out){
  int idx = blockIdx.x * blockDim.x + threadIdx.x;
  if (idx >= NE * NCONT * NG) return;
  int j = idx & (NG - 1);
  int t = (idx >> 9) % NCONT;
  int e = idx / (NCONT * NG);
  float s = bias[e * NG + j];
  #pragma unroll
  for (int i = 0; i < ND; ++i)
    s += feats[t * ND + i] * W[(e * 9 + 1 + i) * NG + j];
  float sc = ((j >> 7) == 2) ? S_TANH : S_SIG;
  out[idx] = s * sc;
}

__global__ void prep_fxw_dec(const float* __restrict__ feats, const float* __restrict__ W,
                             const float* __restrict__ bias, float* __restrict__ out){
  int idx = blockIdx.x * blockDim.x + threadIdx.x;
  if (idx >= NE * NHOR * NG) return;
  int j = idx & (NG - 1);
  int t = (idx >> 9) % NHOR;
  int e = idx / (NHOR * NG);
  float s = bias[e * NG + j];
  #pragma unroll
  for (int i = 0; i < ND; ++i)
    s += feats[(NCONT + t) * ND + i] * W[(e * ND + i) * NG + j];
  float sc = ((j >> 7) == 2) ? S_TANH : S_SIG;
  out[idx] = s * sc;
}

__global__ void prep_node(const int* __restrict__ nid, const float* __restrict__ emb,
                          float* __restrict__ node_w){
  int b = blockIdx.x * blockDim.x + threadIdx.x;
  if (b >= NB) return;
  int n = nid[b];
  float a[NE]; float s = 0.f;
  #pragma unroll
  for (int e = 0; e < NE; ++e){ a[e] = fabsf(emb[n * NE + e]); s += a[e]; }
  float inv = 1.0f / s;
  #pragma unroll
  for (int e = 0; e < NE; ++e) node_w[b * NE + e] = a[e] * inv;
}

// One block = (expert e, 64 batch rows). 512 threads = 8 waves.
// MFMA roles: A = U^T frags (regs, pre-scaled per gate), B = h frags (LDS),
// C-in = pre-scaled fx. Step is software-pipelined over nf so the cell VALU/
// trans work of fragment nf-1 overlaps the MFMA block of fragment nf.
__global__ __launch_bounds__(512, 2) void lstm_main(
    const float* __restrict__ y_prev,
    const float* __restrict__ enc_W,
    const float* __restrict__ enc_U,
    const float* __restrict__ dec_U,
    const float* __restrict__ out_w,
    const float* __restrict__ fxw_enc,
    const float* __restrict__ fxw_dec,
    float* __restrict__ ws_out)
{
  __shared__ unsigned short hl[2][BT * NH];  // 2 x 16 KB, XOR-swizzled rows
  __shared__ float part[2][BT][9];           // decoder partials (+1 pad col)

  const int tid  = threadIdx.x;
  const int lane = tid & 63;
  const int w    = tid >> 6;
  const int e    = blockIdx.x & 7;
  const int b0   = (blockIdx.x >> 3) * BT;
  const int l15  = lane & 15;
  const int l4   = lane >> 4;              // 0..3
  const int hc0  = w * 16 + l4 * 4;        // thread's hidden-col base (rg adds 0..3)

  // precomputed swizzled LDS byte addresses (step-invariant)
  const int q   = (l15 >> 2) & 1;
  const int Ae  = l15 * 128 + ((l4 ^ (l15 & 3)) << 3);
  const int rb0 = 2 * (Ae + q * 32);
  const int rb1 = 2 * (Ae + (1 - q) * 32);
  const int wb  = 2 * ((l15 * 128 + hc0) ^ ((l15 & 7) << 3));

  { // init h buffer 0 = 0
    f32x4 z4 = {0.f, 0.f, 0.f, 0.f};
    ((f32x4*)&hl[0][0])[tid]       = z4;
    ((f32x4*)&hl[0][0])[tid + 512] = z4;
  }

  // A-frags: ut[g][kc], lane holds sc[g]*U[k = 32kc+8*l4+j][128g + w*16 + l15]
  bf16x8 ut[4][4];
  {
    const float* Ub = enc_U + e * NH * NG + w * 16 + l15;
    #pragma unroll
    for (int g = 0; g < 4; ++g){
      float scg = (g == 2) ? S_TANH : S_SIG;
      #pragma unroll
      for (int kc = 0; kc < 4; ++kc){
        const float* p = Ub + (kc * 32 + l4 * 8) * NG + g * NH;
        bf16x8 v;
        #pragma unroll
        for (int j = 0; j < 8; ++j) v[j] = (short)f2bf(p[j * NG] * scg);
        ut[g][kc] = v;
      }
    }
  }

  // encoder y-weight row, packed halves, pre-scaled
  f32x2 w042[4][2];
  #pragma unroll
  for (int g = 0; g < 4; ++g){
    float scg = (g == 2) ? S_TANH : S_SIG;
    f32x4 t4 = *(const f32x4*)&enc_W[(e * 9) * NG + g * NH + hc0];
    t4 *= scg;
    w042[g][0] = lo2(t4); w042[g][1] = hi2(t4);
  }

  f32x2 cs2[4][2];   // scaled cell state c_s = 2log2e * c
  #pragma unroll
  for (int nf = 0; nf < 4; ++nf){ cs2[nf][0] = splat2(0.f); cs2[nf][1] = splat2(0.f); }

  f32x2 ow2[2];      // decoder out weights (set later)
  f32x4 fxv[4];      // prefetched fx for current step
  float yv[4];       // prefetched y for current step

  const float* fxe = fxw_enc + e * NCONT * NG;
  const float* yp  = y_prev + b0;

  // prologue prefetch t=0
  #pragma unroll
  for (int g = 0; g < 4; ++g) fxv[g] = *(const f32x4*)&fxe[g * NH + hc0];
  #pragma unroll
  for (int nf = 0; nf < 4; ++nf) yv[nf] = yp[nf * 16 + l15];

  __syncthreads();

  // read the 4 B-frags (kc 0..3) of fragment-row nf from buffer B
  auto rdnf = [&](auto Bc, auto NFc, bf16x8* hb){
    constexpr int B  = decltype(Bc)::value;
    constexpr int nf = decltype(NFc)::value;
    #pragma unroll
    for (int kc = 0; kc < 4; ++kc)
      hb[kc] = *(const bf16x8*)((const char*)hl +
                 (B * 16384 + nf * 4096 + (kc >> 1) * 128) + ((kc & 1) ? rb1 : rb0));
  };
  // 16 MFMAs for one nf (C-in = fx)
  auto mmnf = [&](bf16x8* hb, f32x4* ag){
    #pragma unroll
    for (int g = 0; g < 4; ++g)
      ag[g] = __builtin_amdgcn_mfma_f32_16x16x32_bf16(ut[g][0], hb[0], fxv[g], 0, 0, 0);
    #pragma unroll
    for (int kc = 1; kc < 4; ++kc)
      #pragma unroll
      for (int g = 0; g < 4; ++g)
        ag[g] = __builtin_amdgcn_mfma_f32_16x16x32_bf16(ut[g][kc], hb[kc], ag[g], 0, 0, 0);
  };
  // cell math + h write for one nf
  auto cellnf = [&](auto Bc, auto ENCc, auto NFc, f32x4* ag, float ycur, float* pout){
    constexpr int  B   = decltype(Bc)::value;
    constexpr bool ENC = decltype(ENCc)::value;
    constexpr int  nf  = decltype(NFc)::value;
    f32x2 h2[2];
    #pragma unroll
    for (int hf = 0; hf < 2; ++hf){
      f32x2 zi = hf ? hi2(ag[0]) : lo2(ag[0]);
      f32x2 zf = hf ? hi2(ag[1]) : lo2(ag[1]);
      f32x2 zg = hf ? hi2(ag[2]) : lo2(ag[2]);
      f32x2 zo = hf ? hi2(ag[3]) : lo2(ag[3]);
      if constexpr (ENC){
        f32x2 y2 = splat2(ycur);
        zi = fma2(y2, w042[0][hf], zi);
        zf = fma2(y2, w042[1][hf], zf);
        zg = fma2(y2, w042[2][hf], zg);
        zo = fma2(y2, w042[3][hf], zo);
      }
      f32x2 gi = gate2(zi);                 // sigmoid(i)
      f32x2 gf = gate2(zf);                 // sigmoid(f)
      f32x2 go = gate2(zo);                 // sigmoid(o)
      f32x2 rg_ = gate2(zg);                // rcp(1+exp2(zg_s))
      f32x2 gg2 = fma2(rg_, splat2(-2.0f * S_TANH), splat2(S_TANH)); // 2log2e*tanh(g)
      f32x2 c  = fma2(gf, cs2[nf][hf], gi * gg2);   // scaled cell state
      cs2[nf][hf] = c;
      f32x2 rc = gate2(c);                  // rcp(1+exp2(c_s))
      f32x2 th = fma2(rc, splat2(-2.0f), splat2(1.0f));  // tanh(c)
      h2[hf] = go * th;
    }
    u32x2 pk;
    pk.x = cvt_pk_bf16(h2[0].x, h2[0].y);
    pk.y = cvt_pk_bf16(h2[1].x, h2[1].y);
    *(u32x2*)((char*)hl + ((B ^ 1) * 16384 + nf * 4096) + wb) = pk;
    if constexpr (!ENC){
      f32x2 pp = fma2(h2[0], ow2[0], h2[1] * ow2[1]);
      pout[nf] = pp.x + pp.y;
    }
  };

  // ---- one LSTM step, nf-pipelined: C(nf-1) overlaps M(nf) ----
  auto step = [&](auto Bc, auto ENCc, const float* fxn, const float* ypn, float* pout){
    constexpr bool ENC = decltype(ENCc)::value;

    float ycur[4];
    if constexpr (ENC){
      #pragma unroll
      for (int nf = 0; nf < 4; ++nf) ycur[nf] = yv[nf];
    }

    bf16x8 hbA[4], hbB[4];
    f32x4 a0[4], a1[4], a2[4], a3[4];

    rdnf(Bc, ic<0>{}, hbA); mmnf(hbA, a0);
    rdnf(Bc, ic<1>{}, hbB); mmnf(hbB, a1);
    cellnf(Bc, ENCc, ic<0>{}, a0, ycur[0], pout);
    rdnf(Bc, ic<2>{}, hbA); mmnf(hbA, a2);
    cellnf(Bc, ENCc, ic<1>{}, a1, ycur[1], pout);
    rdnf(Bc, ic<3>{}, hbB); mmnf(hbB, a3);
    // prefetch next step's fx/y under the remaining cell math
    #pragma unroll
    for (int g = 0; g < 4; ++g) fxv[g] = *(const f32x4*)&fxn[g * NH + hc0];
    if constexpr (ENC){
      #pragma unroll
      for (int nf = 0; nf < 4; ++nf) yv[nf] = ypn[nf * 16 + l15];
    }
    cellnf(Bc, ENCc, ic<2>{}, a2, ycur[2], pout);
    cellnf(Bc, ENCc, ic<3>{}, a3, ycur[3], pout);
    __syncthreads();
  };

  // ---------------- encoder: 168 steps ----------------
  for (int t = 0; t < NCONT; t += 2){
    step(ic<0>{}, std::true_type{}, fxe + NG, yp + NB, nullptr);
    const float* fx2 = (t + 2 < NCONT) ? fxe + 2 * NG : fxe;
    const float* yp2 = (t + 2 < NCONT) ? yp + 2 * NB  : yp;
    step(ic<1>{}, std::true_type{}, fx2, yp2, nullptr);
    fxe += 2 * NG; yp += 2 * NB;
  }

  // decoder A-frags (pre-scaled)
  {
    const float* Ub = dec_U + e * NH * NG + w * 16 + l15;
    #pragma unroll
    for (int g = 0; g < 4; ++g){
      float scg = (g == 2) ? S_TANH : S_SIG;
      #pragma unroll
      for (int kc = 0; kc < 4; ++kc){
        const float* p = Ub + (kc * 32 + l4 * 8) * NG + g * NH;
        bf16x8 v;
        #pragma unroll
        for (int j = 0; j < 8; ++j) v[j] = (short)f2bf(p[j * NG] * scg);
        ut[g][kc] = v;
      }
    }
  }
  {
    f32x4 ow4 = *(const f32x4*)&out_w[e * NH + hc0];
    ow2[0] = lo2(ow4); ow2[1] = hi2(ow4);
  }

  const float* fxd = fxw_dec + e * NHOR * NG;
  #pragma unroll
  for (int g = 0; g < 4; ++g) fxv[g] = *(const f32x4*)&fxd[g * NH + hc0];

  auto emit = [&](int t, float* pbuf){
    #pragma unroll
    for (int nf = 0; nf < 4; ++nf){
      pbuf[nf] += __shfl_xor(pbuf[nf], 16);
      pbuf[nf] += __shfl_xor(pbuf[nf], 32);
    }
    int pb = t & 1;
    if (lane < 16){
      #pragma unroll
      for (int nf = 0; nf < 4; ++nf) part[pb][nf * 16 + l15][w] = pbuf[nf];
    }
    __syncthreads();
    if (w == 0){
      float s = 0.f;
      #pragma unroll
      for (int ww = 0; ww < 8; ++ww) s += part[pb][lane][ww];
      ws_out[(e * NHOR + t) * NB + b0 + lane] = s;
    }
  };

  // ---------------- decoder: 24 steps ----------------
  #pragma unroll 1
  for (int td = 0; td < NHOR; td += 2){
    float pbuf[4];
    step(ic<0>{}, std::false_type{}, fxd + NG, nullptr, pbuf);
    emit(td, pbuf);
    const float* fx2 = (td + 2 < NHOR) ? fxd + 2 * NG : fxd;
    step(ic<1>{}, std::false_type{}, fx2, nullptr, pbuf);
    emit(td + 1, pbuf);
    fxd += 2 * NG;
  }
}

__global__ void finalize(const float* __restrict__ ws_out, const float* __restrict__ node_w,
                         float* __restrict__ out){
  int idx = blockIdx.x * blockDim.x + threadIdx.x;
  if (idx >= NHOR * NB) return;
  int b = idx & (NB - 1);
  float s = 0.f;
  #pragma unroll
  for (int e = 0; e < NE; ++e)
    s += ws_out[e * NHOR * NB + idx] * node_w[b * NE + e];
  out[idx] = s;
}

extern "C" void kernel_launch(void* const* d_in, const int* in_sizes, int n_in,
                              void* d_out, int out_size, void* d_ws, size_t ws_size,
                              hipStream_t stream) {
  const float* feats  = (const float*)d_in[0];
  const float* y_prev = (const float*)d_in[1];
  const int*   nid    = (const int*)  d_in[2];
  const float* emb    = (const float*)d_in[3];
  const float* enc_W  = (const float*)d_in[4];
  const float* enc_U  = (const float*)d_in[5];
  const float* enc_b  = (const float*)d_in[6];
  const float* dec_W  = (const float*)d_in[7];
  const float* dec_U  = (const float*)d_in[8];
  const float* dec_b  = (const float*)d_in[9];
  const float* out_w  = (const float*)d_in[10];
  float* out = (float*)d_out;

  float* ws      = (float*)d_ws;
  float* fxw_enc = ws;
  float* fxw_dec = fxw_enc + NE * NCONT * NG;
  float* node_w  = fxw_dec + NE * NHOR * NG;
  float* ws_out  = node_w + NB * NE;

  prep_fxw_enc<<<(NE * NCONT * NG + 255) / 256, 256, 0, stream>>>(feats, enc_W, enc_b, fxw_enc);
  prep_fxw_dec<<<(NE * NHOR * NG + 255) / 256, 256, 0, stream>>>(feats, dec_W, dec_b, fxw_dec);
  prep_node<<<(NB + 255) / 256, 256, 0, stream>>>(nid, emb, node_w);
  lstm_main<<<NE * (NB / BT), 512, 0, stream>>>(y_prev, enc_W, enc_U, dec_U, out_w,
                                                fxw_enc, fxw_dec, ws_out);
  finalize<<<(NHOR * NB + 255) / 256, 256, 0, stream>>>(ws_out, node_w, out);
}